// Round 1
// baseline (133.514 us; speedup 1.0000x reference)
//
#include <hip/hip_runtime.h>
#include <cstdint>

// entmax (alpha=1.5) via bisection, faithful to entmax.EntmaxBisectFunction.
// alpha-1 = 0.5  =>  inv = 2.0  =>  max(Xs - tau, 0)^inv is a plain square.
//
// One wave (64 lanes) per row of D=2048. Row cached in 32 VGPRs/lane.
// Elements with Xs <= max-1 (= initial tau_lo) can never contribute to any
// f(tau_m) evaluation nor to the final p (all probed tau >= tau_lo), so we
// compact the active set into LDS once and bisect only over it.

constexpr int D   = 2048;
constexpr int EPL = D / 64;      // 32 elements per lane
constexpr int VPL = EPL / 4;     // 8 float4 per lane
constexpr int ROWS_PER_BLOCK = 4;
// (1/2048)^0.5
constexpr float TAU_HI_OFF = 0.022097086912079608f;
constexpr float NEG = -1e30f;

__global__ __launch_bounds__(256)
void entmax_bisect_kernel(const float* __restrict__ X,
                          float* __restrict__ out,
                          int nrows)
{
    __shared__ float sm[ROWS_PER_BLOCK][D];

    const int wv   = threadIdx.x >> 6;
    const int lane = threadIdx.x & 63;
    const int row  = blockIdx.x * ROWS_PER_BLOCK + wv;
    if (row >= nrows) return;

    const float4* __restrict__ xv =
        reinterpret_cast<const float4*>(X + (size_t)row * D);
    float4* __restrict__ ov =
        reinterpret_cast<float4*>(out + (size_t)row * D);

    // ---- load row, scale by (alpha-1)=0.5, running max ----
    float xs[EPL];
    float m = NEG;
    #pragma unroll
    for (int j = 0; j < VPL; ++j) {
        float4 v = xv[lane + 64 * j];
        xs[4*j+0] = v.x * 0.5f;
        xs[4*j+1] = v.y * 0.5f;
        xs[4*j+2] = v.z * 0.5f;
        xs[4*j+3] = v.w * 0.5f;
        m = fmaxf(m, fmaxf(fmaxf(xs[4*j+0], xs[4*j+1]),
                           fmaxf(xs[4*j+2], xs[4*j+3])));
    }
    #pragma unroll
    for (int off = 32; off > 0; off >>= 1)
        m = fmaxf(m, __shfl_xor(m, off, 64));

    const float tau_lo0 = m - 1.0f;
    const float tau_hi  = m - TAU_HI_OFF;

    // ---- f_lo over all elements + ballot-compact actives into LDS ----
    float* srow = sm[wv];
    float acc = 0.0f;
    int base = 0;
    #pragma unroll
    for (int e = 0; e < EPL; ++e) {
        float t = xs[e] - tau_lo0;
        bool active = t > 0.0f;
        float tc = active ? t : 0.0f;
        acc = fmaf(tc, tc, acc);
        unsigned long long bal = __ballot(active);
        int idx = base + __popcll(bal & ((1ull << lane) - 1ull));
        if (active) srow[idx] = xs[e];
        base += (int)__popcll(bal);
    }
    #pragma unroll
    for (int off = 32; off > 0; off >>= 1)
        acc += __shfl_xor(acc, off, 64);
    const float f_lo = acc - 1.0f;

    const int k = base;                 // active count, >= 1 (the max element)
    const int nchunk = (k + 63) >> 6;   // LDS chunks of 64

    // first chunk lives in a register: common case (k <= 64) never touches
    // LDS inside the bisection loop
    const float v0 = (lane < k) ? srow[lane] : NEG;

    // ---- 50 bisection iterations on the active set ----
    float tau_lo = tau_lo0;
    float dm     = tau_hi - tau_lo0;
    float tau_m  = tau_lo0;
    for (int it = 0; it < 50; ++it) {
        dm *= 0.5f;
        tau_m = tau_lo + dm;
        float t0 = fmaxf(v0 - tau_m, 0.0f);
        float a  = t0 * t0;
        for (int j = 1; j < nchunk; ++j) {
            int i = (j << 6) + lane;
            float v = (i < k) ? srow[i] : NEG;
            float t = fmaxf(v - tau_m, 0.0f);
            a = fmaf(t, t, a);
        }
        #pragma unroll
        for (int off = 32; off > 0; off >>= 1)
            a += __shfl_xor(a, off, 64);
        float f_m = a - 1.0f;
        if (f_m * f_lo >= 0.0f) tau_lo = tau_m;
    }

    // ---- normalization sum from the active set at final tau_m ----
    float t0 = fmaxf(v0 - tau_m, 0.0f);
    float s  = t0 * t0;
    for (int j = 1; j < nchunk; ++j) {
        int i = (j << 6) + lane;
        float v = (i < k) ? srow[i] : NEG;
        float t = fmaxf(v - tau_m, 0.0f);
        s = fmaf(t, t, s);
    }
    #pragma unroll
    for (int off = 32; off > 0; off >>= 1)
        s += __shfl_xor(s, off, 64);
    const float invs = 1.0f / s;

    // ---- dense output from the register copy ----
    #pragma unroll
    for (int j = 0; j < VPL; ++j) {
        float4 o;
        float a0 = fmaxf(xs[4*j+0] - tau_m, 0.0f);
        float a1 = fmaxf(xs[4*j+1] - tau_m, 0.0f);
        float a2 = fmaxf(xs[4*j+2] - tau_m, 0.0f);
        float a3 = fmaxf(xs[4*j+3] - tau_m, 0.0f);
        o.x = a0 * a0 * invs;
        o.y = a1 * a1 * invs;
        o.z = a2 * a2 * invs;
        o.w = a3 * a3 * invs;
        ov[lane + 64 * j] = o;
    }
}

extern "C" void kernel_launch(void* const* d_in, const int* in_sizes, int n_in,
                              void* d_out, int out_size, void* d_ws, size_t ws_size,
                              hipStream_t stream)
{
    const float* X = (const float*)d_in[0];
    float* O = (float*)d_out;
    const int nrows = in_sizes[0] / D;
    const int blocks = (nrows + ROWS_PER_BLOCK - 1) / ROWS_PER_BLOCK;
    hipLaunchKernelGGL(entmax_bisect_kernel, dim3(blocks), dim3(256), 0, stream,
                       X, O, nrows);
}

// Round 2
// 45.990 us; speedup vs baseline: 2.9031x; 2.9031x over previous
//
#include <hip/hip_runtime.h>
#include <cstdint>

// entmax (alpha=1.5) for rows of D=2048 fp32, one wave per row.
// Reference does 50 bisection iterations on f(tau)=sum(max(Xs-tau,0)^2)-1 then
// renormalizes; in fp32 it converges to the exact root tau* (iters >~25 are
// no-ops). We compute the same root by monotone Newton from the lower bracket
// (f is convex, decreasing => Newton from below never overshoots), which takes
// ~8-12 iterations instead of 50.
//
// Scale fold: Xs = X/2. Solve in unscaled y=X for T=2*tau:
//   sum(max(y-T,0)^2) = 4;  p = max(y-T,0)^2 (the /4 cancels in p/sum(p)).
//
// Active-set compaction: all probed T >= T0 = M-2, so elements y <= M-2 never
// contribute. Typical active count k ~ 200 of 2048. Compact them into LDS,
// each lane then holds <=8 compacted values in registers -> Newton loop is
// register-only. k > 512 (adversarial) falls back to the full 32-reg row.

constexpr int D   = 2048;
constexpr int EPL = 32;          // elements per lane
constexpr int VPL = 8;           // float4 per lane
constexpr int RPB = 4;           // rows (waves) per 256-thread block
constexpr int CAP = 512;         // compacted capacity per row
constexpr int CREG = CAP / 64;   // 8 registers per lane
constexpr float NEG = -1e30f;

typedef float vf4 __attribute__((ext_vector_type(4)));

template<int N>
__device__ inline float newton_tau(const float (&v)[N], float T0)
{
    float T = T0;
    #pragma unroll 1
    for (int it = 0; it < 24; ++it) {
        float S = 0.0f, Q = 0.0f;
        #pragma unroll
        for (int r = 0; r < N; ++r) {
            float t = fmaxf(v[r] - T, 0.0f);
            S += t;
            Q = fmaf(t, t, Q);
        }
        #pragma unroll
        for (int off = 32; off > 0; off >>= 1) {
            S += __shfl_xor(S, off, 64);
            Q += __shfl_xor(Q, off, 64);
        }
        // Newton: T += (Q-4)/(2S).  S >= M - T > 0 always (max stays active).
        float step = fmaxf((Q - 4.0f) * 0.5f * __builtin_amdgcn_rcpf(S), 0.0f);
        T += step;
        if (step < 1e-7f) break;   // wave-uniform: S,Q identical on all lanes
    }
    return T;
}

__global__ __launch_bounds__(256)
void entmax_bisect_kernel(const float* __restrict__ X,
                          float* __restrict__ out,
                          int nrows)
{
    __shared__ float sm[RPB][CAP];

    const int wv   = threadIdx.x >> 6;
    const int lane = threadIdx.x & 63;
    const int row  = blockIdx.x * RPB + wv;
    if (row >= nrows) return;

    const float4* __restrict__ xv =
        reinterpret_cast<const float4*>(X + (size_t)row * D);
    vf4* __restrict__ ov =
        reinterpret_cast<vf4*>(out + (size_t)row * D);

    // ---- load row (unscaled), running max ----
    float xs[EPL];
    float M = NEG;
    #pragma unroll
    for (int j = 0; j < VPL; ++j) {
        float4 v = xv[lane + 64 * j];
        xs[4*j+0] = v.x; xs[4*j+1] = v.y; xs[4*j+2] = v.z; xs[4*j+3] = v.w;
        M = fmaxf(M, fmaxf(fmaxf(v.x, v.y), fmaxf(v.z, v.w)));
    }
    #pragma unroll
    for (int off = 32; off > 0; off >>= 1)
        M = fmaxf(M, __shfl_xor(M, off, 64));

    const float thr = M - 2.0f;    // T0 = lower bracket (tau_lo*2)

    // ---- count actives per lane, wave scan for compaction offsets ----
    int c = 0;
    #pragma unroll
    for (int e = 0; e < EPL; ++e) c += (xs[e] > thr) ? 1 : 0;
    int inc = c;
    #pragma unroll
    for (int d2 = 1; d2 < 64; d2 <<= 1) {
        int n = __shfl_up(inc, d2, 64);
        if (lane >= d2) inc += n;
    }
    const int k = __shfl(inc, 63, 64);   // total actives (wave-uniform)

    float T;
    if (k <= CAP) {
        // compact actives into LDS (order irrelevant: we only sum them)
        float* srow = sm[wv];
        int pos = inc - c;
        #pragma unroll
        for (int e = 0; e < EPL; ++e)
            if (xs[e] > thr) srow[pos++] = xs[e];
        float cv[CREG];
        #pragma unroll
        for (int r = 0; r < CREG; ++r) {
            int i = lane + 64 * r;
            cv[r] = (i < k) ? srow[i] : NEG;
        }
        T = newton_tau(cv, thr);
    } else {
        // rare/adversarial rows: Newton over the full register row
        T = newton_tau(xs, thr);
    }

    // ---- normalization sum at final T (overwrite xs with t = max(y-T,0)) ----
    float s = 0.0f;
    #pragma unroll
    for (int e = 0; e < EPL; ++e) {
        float t = fmaxf(xs[e] - T, 0.0f);
        xs[e] = t;
        s = fmaf(t, t, s);
    }
    #pragma unroll
    for (int off = 32; off > 0; off >>= 1)
        s += __shfl_xor(s, off, 64);
    const float inv = 1.0f / s;

    // ---- dense output: p = t^2 / sum(t^2), nontemporal streaming stores ----
    #pragma unroll
    for (int j = 0; j < VPL; ++j) {
        vf4 o;
        o.x = xs[4*j+0] * xs[4*j+0] * inv;
        o.y = xs[4*j+1] * xs[4*j+1] * inv;
        o.z = xs[4*j+2] * xs[4*j+2] * inv;
        o.w = xs[4*j+3] * xs[4*j+3] * inv;
        __builtin_nontemporal_store(o, &ov[lane + 64 * j]);
    }
}

extern "C" void kernel_launch(void* const* d_in, const int* in_sizes, int n_in,
                              void* d_out, int out_size, void* d_ws, size_t ws_size,
                              hipStream_t stream)
{
    const float* X = (const float*)d_in[0];
    float* O = (float*)d_out;
    const int nrows = in_sizes[0] / D;
    const int blocks = (nrows + RPB - 1) / RPB;
    hipLaunchKernelGGL(entmax_bisect_kernel, dim3(blocks), dim3(256), 0, stream,
                       X, O, nrows);
}

// Round 3
// 42.052 us; speedup vs baseline: 3.1750x; 1.0936x over previous
//
#include <hip/hip_runtime.h>
#include <cstdint>

// entmax (alpha=1.5) for rows of D=2048 fp32, one wave per row.
// alpha-1=0.5 => inv=2 => p ~ max(Xs - tau, 0)^2.  Fold the x0.5 scale away:
// solve in unscaled y=X for T=2*tau:  sum(max(y-T,0)^2) = 4; the /4 cancels in
// the final renormalization p/sum(p).
//
// The reference's 50 fp32 bisection iterations converge to the root to ~ulp;
// we find the same root by monotone Newton from the lower bracket T0 = M-2
// (f convex decreasing => Newton from below never overshoots; with target
// constant 4, convergence is superlinear: err' = err^2/(2err+4)).
//   - one full-row Newton step at T0 (fused with the load pass reduction)
//   - compact actives at T1 (typically ~50 of 2048) into LDS, <=2 regs/lane
//   - ~4-6 register-only Newton iterations, fixed-point break (Tn == T)
//   - normalization sum = last Q from the solver (exact at the fixed point)
// k > 128 (adversarial rows, e.g. all-equal) falls back to full-row Newton.

constexpr int D   = 2048;
constexpr int EPL = 32;          // elements per lane
constexpr int VPL = 8;           // float4 per lane
constexpr int RPB = 4;           // rows (waves) per 256-thread block
constexpr int CAP = 128;         // compacted capacity per row
constexpr int CREG = CAP / 64;   // 2 registers per lane
constexpr float NEG = -1e30f;

typedef float vf4 __attribute__((ext_vector_type(4)));

__device__ inline void wred2(float& a, float& b)
{
    #pragma unroll
    for (int off = 32; off > 0; off >>= 1) {
        a += __shfl_xor(a, off, 64);
        b += __shfl_xor(b, off, 64);
    }
}

template<int N>
__device__ inline float newton_loop(const float (&v)[N], float T, float& Qout)
{
    float Qlast = 4.0f;
    #pragma unroll 1
    for (int it = 0; it < 16; ++it) {
        float S = 0.0f, Q = 0.0f;
        #pragma unroll
        for (int r = 0; r < N; ++r) {
            float t = fmaxf(v[r] - T, 0.0f);
            S += t;
            Q = fmaf(t, t, Q);
        }
        wred2(S, Q);                    // wave-uniform S, Q
        Qlast = Q;
        // S >= M - T > 0 always (the max element stays active)
        float step = fmaxf((Q - 4.0f) * 0.5f * __builtin_amdgcn_rcpf(S), 0.0f);
        float Tn = T + step;
        if (Tn == T) break;             // fixed point at fp32 resolution
        T = Tn;
    }
    Qout = Qlast;                       // sum(max(v-T,0)^2) at final T
    return T;
}

__global__ __launch_bounds__(256)
void entmax_bisect_kernel(const float* __restrict__ X,
                          float* __restrict__ out,
                          int nrows)
{
    __shared__ float sm[RPB][CAP];

    const int wv   = threadIdx.x >> 6;
    const int lane = threadIdx.x & 63;
    const int row  = blockIdx.x * RPB + wv;
    if (row >= nrows) return;

    const float4* __restrict__ xv =
        reinterpret_cast<const float4*>(X + (size_t)row * D);
    vf4* __restrict__ ov =
        reinterpret_cast<vf4*>(out + (size_t)row * D);

    // ---- load row, running max ----
    float xs[EPL];
    float M = NEG;
    #pragma unroll
    for (int j = 0; j < VPL; ++j) {
        float4 v = xv[lane + 64 * j];
        xs[4*j+0] = v.x; xs[4*j+1] = v.y; xs[4*j+2] = v.z; xs[4*j+3] = v.w;
        M = fmaxf(M, fmaxf(fmaxf(v.x, v.y), fmaxf(v.z, v.w)));
    }
    #pragma unroll
    for (int off = 32; off > 0; off >>= 1)
        M = fmaxf(M, __shfl_xor(M, off, 64));

    // ---- one full-row Newton step from the lower bracket T0 = M-2 ----
    const float T0 = M - 2.0f;
    float S0 = 0.0f, Q0 = 0.0f;
    #pragma unroll
    for (int e = 0; e < EPL; ++e) {
        float t = fmaxf(xs[e] - T0, 0.0f);
        S0 += t;
        Q0 = fmaf(t, t, Q0);
    }
    wred2(S0, Q0);
    const float T1 = T0 +
        fmaxf((Q0 - 4.0f) * 0.5f * __builtin_amdgcn_rcpf(S0), 0.0f);

    // ---- count actives at T1, wave scan for compaction offsets ----
    int c = 0;
    #pragma unroll
    for (int e = 0; e < EPL; ++e) c += (xs[e] > T1) ? 1 : 0;
    int inc = c;
    #pragma unroll
    for (int d2 = 1; d2 < 64; d2 <<= 1) {
        int n = __shfl_up(inc, d2, 64);
        if (lane >= d2) inc += n;
    }
    const int k = __shfl(inc, 63, 64);   // total actives (wave-uniform), >= 1

    float T, Qf;
    if (k <= CAP) {
        // compact actives into LDS; same-wave write->read, no barrier needed
        float* srow = sm[wv];
        int pos = inc - c;
        #pragma unroll
        for (int e = 0; e < EPL; ++e)
            if (xs[e] > T1) srow[pos++] = xs[e];
        float cv[CREG];
        #pragma unroll
        for (int r = 0; r < CREG; ++r) {
            int i = lane + 64 * r;
            cv[r] = (i < k) ? srow[i] : NEG;
        }
        T = newton_loop(cv, T1, Qf);
    } else {
        // rare/adversarial rows: Newton over the full register row
        T = newton_loop(xs, T1, Qf);
    }

    const float inv = 1.0f / Qf;

    // ---- dense output: p = max(y-T,0)^2 / Q, nontemporal streaming stores ----
    #pragma unroll
    for (int j = 0; j < VPL; ++j) {
        float a0 = fmaxf(xs[4*j+0] - T, 0.0f);
        float a1 = fmaxf(xs[4*j+1] - T, 0.0f);
        float a2 = fmaxf(xs[4*j+2] - T, 0.0f);
        float a3 = fmaxf(xs[4*j+3] - T, 0.0f);
        vf4 o;
        o.x = a0 * a0 * inv;
        o.y = a1 * a1 * inv;
        o.z = a2 * a2 * inv;
        o.w = a3 * a3 * inv;
        __builtin_nontemporal_store(o, &ov[lane + 64 * j]);
    }
}

extern "C" void kernel_launch(void* const* d_in, const int* in_sizes, int n_in,
                              void* d_out, int out_size, void* d_ws, size_t ws_size,
                              hipStream_t stream)
{
    const float* X = (const float*)d_in[0];
    float* O = (float*)d_out;
    const int nrows = in_sizes[0] / D;
    const int blocks = (nrows + RPB - 1) / RPB;
    hipLaunchKernelGGL(entmax_bisect_kernel, dim3(blocks), dim3(256), 0, stream,
                       X, O, nrows);
}